// Round 10
// baseline (101.181 us; speedup 1.0000x reference)
//
#include <hip/hip_runtime.h>
#include <hip/hip_fp16.h>
#include <math.h>

#define RES 256
#define TPAD 364              // padded texture dim: image coords -53..310
#define N_ANGLES 256
#define NA2 129               // paired angle slots: i and 256-i
#define BATCH 8
#define ROWB (TPAD * 16)      // global plane row pitch bytes

#define SCH 16                // s per block
#define TCH 64                // t per block
#define NTC 4                 // 256 / TCH
#define BROWS 72              // band rows in LDS
#define PLANE_TEX (BROWS * 32)      // 2304 texels/plane
#define PLANE_B (PLANE_TEX * 16)    // 36864 bytes (ds offset immediate!)

typedef _Float16 h2 __attribute__((ext_vector_type(2)));
__device__ inline h2 u2h(unsigned u) { return __builtin_bit_cast(h2, u); }
__device__ inline unsigned h2u(h2 h) { return __builtin_bit_cast(unsigned, h); }

// Four global planes of 16B texels (8 x fp16), each TPAD x TPAD, zero outside:
//   0: normal, image   1: normal, x-flipped   2: transposed   3: transposed, x-flip
__global__ void prep_pack(const float* __restrict__ imgs,
                          unsigned int* __restrict__ W) {
    int idx = blockIdx.x * blockDim.x + threadIdx.x;
    const int total = 4 * TPAD * TPAD * 4;
    if (idx >= total) return;
    int pair  = idx & 3;
    int px    = (idx >> 2) % (TPAD * TPAD);
    int plane = (idx >> 2) / (TPAD * TPAD);
    int orient = plane >> 1, side = plane & 1;
    int ct = px % TPAD, rt = px / TPAD;
    int ri = rt - 53, ci = ct - 53;
    int row, col;
    if (orient == 0) { row = ri; col = side ? (255 - ci) : ci; }
    else             { row = ci; col = side ? (255 - ri) : ri; }
    float v0 = 0.0f, v1 = 0.0f;
    if ((unsigned)row < RES && (unsigned)col < RES) {
        const float* p = imgs + ((size_t)(pair * 2) * RES + row) * RES + col;
        v0 = p[0];
        v1 = p[RES * RES];
    }
    __half2 h = __halves2half2(__float2half_rn(v0), __float2half_rn(v1));
    W[((size_t)plane * TPAD * TPAD + px) * 4 + pair] =
        *reinterpret_cast<unsigned int*>(&h);
}

// Block = (angle-pair, 16 s, 64 t). Stage sheared band (norm+flip) into LDS
// with mod-32 column slots (+XOR-3 bank swizzle), sample fully per-lane.
__global__ __launch_bounds__(256) void radon_kernel(
        const char* __restrict__ TEX,
        const float* __restrict__ angles,
        __half* __restrict__ part) {
    __shared__ uint4 band[2 * PLANE_TEX];   // 73728 B; scr aliases it afterwards

    const int tid = threadIdx.x;
    const int sl  = tid & 15;
    const int tl  = tid >> 4;              // 0..15
    const int a   = blockIdx.x;            // 0..128
    const int s0  = blockIdx.y * SCH;
    const int tc  = blockIdx.z;
    const int t0  = tc * TCH;

    float theta = angles[a];
    float sn, cs;
    sincosf(theta, &sn, &cs);

    const size_t planeGB = (size_t)TPAD * TPAD * 16;
    float Rs, Rt, Cs, Ct;
    const char *gN, *gF;
    if (fabsf(cs) >= fabsf(sn)) {
        Rs = sn; Rt = cs;  Cs = cs; Ct = -sn;
        gN = TEX;                gF = TEX + planeGB;
    } else {
        Rs = cs; Rt = -sn; Cs = sn; Ct = cs;
        gN = TEX + 2 * planeGB;  gF = TEX + 3 * planeGB;
    }

    const float m = Ct / Rt;                       // |m| <= 1
    // block-center coords and band origin
    const float smc = (float)s0 - 120.0f;          // s0+7.5-127.5
    const float tmc = (float)t0 - 96.0f;           // t0+31.5-127.5
    const float prc = fmaf(smc, Rs, fmaf(tmc, Rt, 180.5f));
    const float pcc = fmaf(smc, Cs, fmaf(tmc, Ct, 180.5f));
    const int   r0  = (int)floorf(prc - 7.5f * fabsf(Rs) - 31.5f * fabsf(Rt)) - 2;
    const float ku  = Cs - m * Rs;                 // du/ds (= +-1/Rt)
    const float ubase = (pcc - m * prc) - 7.5f * fabsf(ku) - 3.0f;

    // per-thread ray
    const float s_c = (float)(s0 + sl) - 127.5f;
    const float prA = fmaf(s_c, Rs, 180.5f);
    const float pcA = fmaf(s_c, Cs, 180.5f);
    const float pr0 = prA - 127.5f * Rt;           // value at t-index 0
    const float pc0 = pcA - 127.5f * Ct;

    // work-skip clip: nonzero bilinear only for padded coords in [52, 309]
    const float LO = 52.0f, HI = 309.0f;
    float tmin = 0.0f, tmax = 255.0f;
    {
        float inv = 1.0f / Rt;
        float ta = (LO - pr0) * inv, tb = (HI - pr0) * inv;
        tmin = fmaxf(tmin, fminf(ta, tb));
        tmax = fminf(tmax, fmaxf(ta, tb));
    }
    if (fabsf(Ct) > 1e-6f) {
        float inv = 1.0f / Ct;
        float ta = (LO - pc0) * inv, tb = (HI - pc0) * inv;
        tmin = fmaxf(tmin, fminf(ta, tb));
        tmax = fminf(tmax, fmaxf(ta, tb));
    } else if (!(pc0 >= LO && pc0 <= HI)) {
        tmax = -1.0f;
    }
    // this thread's t = t0 + tl + 16k
    int ik0 = (int)ceilf((tmin - (float)(t0 + tl)) * 0.0625f);
    int ik1 = (int)floorf((tmax - (float)(t0 + tl)) * 0.0625f);
    int kmin = max(ik0, 0), kmax = min(ik1, 3);

    h2 nA0 = {}, nA1 = {}, nA2 = {}, nA3 = {};     // norm accumulators
    h2 fA0 = {}, fA1 = {}, fA2 = {}, fA3 = {};     // flip accumulators

    int anywork = __syncthreads_or(kmin <= kmax);
    if (anywork) {
        // ---- stage band: 2304 texels x 2 planes, coalesced 32-texel rows ----
        #pragma unroll
        for (int it = 0; it < 9; ++it) {
            int idx = tid + it * 256;
            int rs = idx >> 5, j = idx & 31;
            int r  = r0 + rs;
            int cb = (int)floorf(fmaf((float)r, m, ubase));
            int c  = cb + j;
            uint4 vn = make_uint4(0u, 0u, 0u, 0u);
            uint4 vf = vn;
            if (r >= 53 && r <= 308 && c >= 53 && c <= 308) {
                size_t go = (size_t)r * ROWB + (size_t)c * 16;
                vn = *(const uint4*)(gN + go);
                vf = *(const uint4*)(gF + go);
            }
            unsigned ad = ((unsigned)rs << 9)
                        + ((((unsigned)c & 31u) << 4) ^ ((((unsigned)(rs * 3)) & 31u) << 4));
            *(uint4*)((char*)band + ad) = vn;
            *(uint4*)((char*)band + ad + PLANE_B) = vf;
        }
        __syncthreads();

        // ---- sample: one lane = one (s, t) sample, 4 taps x 2 planes ----
        const char* bb = (const char*)band;
        float tcur = (float)(t0 + tl + 16 * kmin) - 127.5f;
        for (int k = kmin; k <= kmax; ++k) {
            float ppr = fmaf(tcur, Rt, prA);
            float ppc = fmaf(tcur, Ct, pcA);
            tcur += 16.0f;
            float wy, wx;
            int ir, ic;
            asm("v_fract_f32 %0, %1"       : "=v"(wy) : "v"(ppr));
            asm("v_fract_f32 %0, %1"       : "=v"(wx) : "v"(ppc));
            asm("v_cvt_flr_i32_f32 %0, %1" : "=v"(ir) : "v"(ppr));
            asm("v_cvt_flr_i32_f32 %0, %1" : "=v"(ic) : "v"(ppc));
            int rs0 = ir - r0;
            unsigned row0 = (unsigned)rs0 << 9;
            unsigned row1 = row0 + 512u;
            unsigned sw0 = (((unsigned)(rs0 * 3)) & 31u) << 4;
            unsigned sw1 = (((unsigned)(rs0 * 3 + 3)) & 31u) << 4;
            unsigned u0 = ((unsigned)ic & 31u) << 4;
            unsigned u1 = ((unsigned)(ic + 1) & 31u) << 4;
            unsigned a00 = row0 + (u0 ^ sw0), a01 = row0 + (u1 ^ sw0);
            unsigned a10 = row1 + (u0 ^ sw1), a11 = row1 + (u1 ^ sw1);

            uint4 n00 = *(const uint4*)(bb + a00);
            uint4 n01 = *(const uint4*)(bb + a01);
            uint4 n10 = *(const uint4*)(bb + a10);
            uint4 n11 = *(const uint4*)(bb + a11);
            uint4 f00 = *(const uint4*)(bb + a00 + PLANE_B);
            uint4 f01 = *(const uint4*)(bb + a01 + PLANE_B);
            uint4 f10 = *(const uint4*)(bb + a10 + PLANE_B);
            uint4 f11 = *(const uint4*)(bb + a11 + PLANE_B);

            float wx1 = 1.0f - wx, wy1 = 1.0f - wy;
            float w00f = wy1 * wx1, w01f = wy1 * wx;
            float w10f = wy  * wx1, w11f = wy  * wx;
            auto pk = [](float x) {
                auto v = __builtin_amdgcn_cvt_pkrtz(x, x);
                return __builtin_bit_cast(h2, v);
            };
            h2 w00 = pk(w00f), w01 = pk(w01f), w10 = pk(w10f), w11 = pk(w11f);

            nA0 = w00 * u2h(n00.x) + nA0;  nA1 = w00 * u2h(n00.y) + nA1;
            nA2 = w00 * u2h(n00.z) + nA2;  nA3 = w00 * u2h(n00.w) + nA3;
            nA0 = w01 * u2h(n01.x) + nA0;  nA1 = w01 * u2h(n01.y) + nA1;
            nA2 = w01 * u2h(n01.z) + nA2;  nA3 = w01 * u2h(n01.w) + nA3;
            nA0 = w10 * u2h(n10.x) + nA0;  nA1 = w10 * u2h(n10.y) + nA1;
            nA2 = w10 * u2h(n10.z) + nA2;  nA3 = w10 * u2h(n10.w) + nA3;
            nA0 = w11 * u2h(n11.x) + nA0;  nA1 = w11 * u2h(n11.y) + nA1;
            nA2 = w11 * u2h(n11.z) + nA2;  nA3 = w11 * u2h(n11.w) + nA3;

            fA0 = w00 * u2h(f00.x) + fA0;  fA1 = w00 * u2h(f00.y) + fA1;
            fA2 = w00 * u2h(f00.z) + fA2;  fA3 = w00 * u2h(f00.w) + fA3;
            fA0 = w01 * u2h(f01.x) + fA0;  fA1 = w01 * u2h(f01.y) + fA1;
            fA2 = w01 * u2h(f01.z) + fA2;  fA3 = w01 * u2h(f01.w) + fA3;
            fA0 = w10 * u2h(f10.x) + fA0;  fA1 = w10 * u2h(f10.y) + fA1;
            fA2 = w10 * u2h(f10.z) + fA2;  fA3 = w10 * u2h(f10.w) + fA3;
            fA0 = w11 * u2h(f11.x) + fA0;  fA1 = w11 * u2h(f11.y) + fA1;
            fA2 = w11 * u2h(f11.z) + fA2;  fA3 = w11 * u2h(f11.w) + fA3;
        }
        __syncthreads();   // band no longer needed; safe to alias as scr
    }

    // ---- reduce over tl: in-wave (lane bits 4-5), then cross-wave via LDS ----
    unsigned vv;
    #define R1632(A) \
        vv = __shfl_xor((int)h2u(A), 16); A = A + u2h(vv); \
        vv = __shfl_xor((int)h2u(A), 32); A = A + u2h(vv);
    R1632(nA0) R1632(nA1) R1632(nA2) R1632(nA3)
    R1632(fA0) R1632(fA1) R1632(fA2) R1632(fA3)
    #undef R1632

    float* scr = (float*)band;                 // [4 waves][16 sl][16 vals]
    const int w = tid >> 6;
    if ((tid & 63) < 16) {
        float* p = scr + (w * 16 + sl) * 16;
        p[0]  = (float)nA0.x;  p[1]  = (float)nA0.y;
        p[2]  = (float)nA1.x;  p[3]  = (float)nA1.y;
        p[4]  = (float)nA2.x;  p[5]  = (float)nA2.y;
        p[6]  = (float)nA3.x;  p[7]  = (float)nA3.y;
        p[8]  = (float)fA0.x;  p[9]  = (float)fA0.y;
        p[10] = (float)fA1.x;  p[11] = (float)fA1.y;
        p[12] = (float)fA2.x;  p[13] = (float)fA2.y;
        p[14] = (float)fA3.x;  p[15] = (float)fA3.y;
    }
    __syncthreads();

    const int o = tid & 15, ss = tid >> 4;
    float sum = scr[(0 * 16 + ss) * 16 + o] + scr[(1 * 16 + ss) * 16 + o]
              + scr[(2 * 16 + ss) * 16 + o] + scr[(3 * 16 + ss) * 16 + o];
    const size_t AR = (size_t)N_ANGLES * RES;
    if (o < 8) {
        part[((size_t)tc * BATCH + o) * AR + (size_t)a * RES + (s0 + ss)] =
            __float2half(sum);
    } else if (a != 0) {
        part[((size_t)tc * BATCH + (o - 8)) * AR
             + (size_t)(N_ANGLES - a) * RES + (s0 + ss)] = __float2half(sum);
    }
}

__global__ void combine(const __half2* __restrict__ p, float2* __restrict__ out) {
    const int n2 = BATCH * N_ANGLES * RES / 2;   // 262144
    int i = blockIdx.x * blockDim.x + threadIdx.x;
    if (i < n2) {
        float2 x0 = __half22float2(p[i]);
        float2 x1 = __half22float2(p[i + n2]);
        float2 x2 = __half22float2(p[i + 2 * n2]);
        float2 x3 = __half22float2(p[i + 3 * n2]);
        out[i] = make_float2(x0.x + x1.x + x2.x + x3.x,
                             x0.y + x1.y + x2.y + x3.y);
    }
}

extern "C" void kernel_launch(void* const* d_in, const int* in_sizes, int n_in,
                              void* d_out, int out_size, void* d_ws, size_t ws_size,
                              hipStream_t stream) {
    const float* imgs   = (const float*)d_in[0];
    const float* angles = (const float*)d_in[1];
    float* out = (float*)d_out;

    const size_t planeGB = (size_t)TPAD * TPAD * 16;         // 2.12 MB
    char*   TEX  = (char*)d_ws;                              // 4 planes, 8.48 MB
    __half* part = (__half*)(TEX + 4 * planeGB);             // 4 x 1 MB fp16

    const int prep_total = 4 * TPAD * TPAD * 4;
    prep_pack<<<(prep_total + 255) / 256, 256, 0, stream>>>(
        imgs, (unsigned int*)TEX);

    dim3 grid(NA2, RES / SCH, NTC);                          // 129 x 16 x 4
    radon_kernel<<<grid, 256, 0, stream>>>(TEX, angles, part);

    const int n2 = BATCH * N_ANGLES * RES / 2;
    combine<<<(n2 + 255) / 256, 256, 0, stream>>>((const __half2*)part, (float2*)out);
}